// Round 8
// baseline (58.759 us; speedup 1.0000x reference)
//
#include <hip/hip_runtime.h>

namespace {

constexpr int IMGSZ = 224;
constexpr int IMG2  = IMGSZ * IMGSZ;   // 50176

// One block = (b, gi). 256 threads = 4 waves. Tables filled once per block:
//   vt[i] = v[i-11-sh] (176, zero-padded), ut[16+j] = u[j] (160, zero-padded)
// Wave w handles 16-row chunks t = w, w+4, ... of this glimpse. Per chunk:
// lanes = (row 0..15) x (seg 0..3); runtime column loop over image-aligned
// 4-col blocks (round-4 champion structure, per-iteration interior check,
// NO template split), H[row][ox] = sum_c S[row][c]*v[c-ox] via compile-time
// register window against the LDS v-table. Shfl-reduce 4 segs -> per-wave
// h_lds[w][16][12]; same-wave read-back accumulates the vertical partial
// into 3 per-lane registers (out elements lane, lane+64, lane+128).
// End: per-wave partials -> osum[4][144] in LDS, one barrier, tid<144 sums
// and stores. No atomics, no memset, single dispatch.
// k = u v^T (rank-1 bicubic): u[r] = k[r][c0], v[c] = k[c0][c] / k[c0][c0].
// Out-of-crop columns contribute 0 via the zero-padded v-table; out-of-range
// vertical taps contribute 0 via the zero-padded u-table.
template <int G>
__device__ void glimpse_bg(
    int b, int gi,
    const float* __restrict__ img, const int* __restrict__ locs,
    const float* __restrict__ kptr, float* __restrict__ out,
    float* __restrict__ vt, float* __restrict__ ut,
    float (*__restrict__ h_lds)[16][12], float (*__restrict__ osum)[144]) {
  constexpr int KSZ  = G - 11;
  constexpr int C0   = KSZ / 2;
  constexpr int NCB2 = (G + 2) / 4 + 1;    // aligned 4-col blocks (covers sh<=3)
  constexpr int NCH  = (G + 15) / 16;      // 16-row chunks
  const int tid = threadIdx.x;
  const int lane = tid & 63;
  const int w = tid >> 6;                  // wave 0..3

  const int x = locs[2 * b];
  const int y = locs[2 * b + 1];
  const int col0 = y - G / 2;
  const int sh = col0 & 3;                 // floor-mod 4 (works for negative)
  const int col_a0 = col0 - sh;            // image-aligned start
  const int cend = col0 + G;
  const float* imgb = img + (size_t)b * (3 * IMG2);

  // cooperative per-block table fill (once, amortized over all chunks)
  {
    const float rpiv = 1.0f / kptr[C0 * KSZ + C0];
    for (int i = tid; i < 176; i += 256) {
      const int kk = i - 11 - sh;
      vt[i] = (kk >= 0 && kk < KSZ) ? kptr[C0 * KSZ + kk] * rpiv : 0.f;
    }
    for (int i = tid; i < 160; i += 256) {
      const int j = i - 16;
      ut[i] = (j >= 0 && j < KSZ) ? kptr[j * KSZ + C0] : 0.f;
    }
  }
  __syncthreads();

  const int row = lane & 15;
  const int seg = lane >> 4;               // 0..3
  const int e0 = lane;                     // owned out elements: e0, e0+64, e0+128
  const int oyA = e0 / 12, oxA = e0 - oyA * 12;
  const int e1 = lane + 64;
  const int oyB = e1 / 12, oxB = e1 - oyB * 12;
  const int e2 = lane + 128;               // only meaningful for lane<16
  const int oyC = e2 / 12, oxC = e2 - oyC * 12;

  float accA = 0.f, accB = 0.f, accC = 0.f;

  for (int t = w; t < NCH; t += 4) {
    const int r0 = t * 16;
    const int row0 = x - G / 2 + r0;
    const int R = (G - r0) < 16 ? (G - r0) : 16;

    float acc[12];
    #pragma unroll
    for (int i = 0; i < 12; ++i) acc[i] = 0.f;

    const int grow = row0 + row;
    if (row < R && (unsigned)grow < (unsigned)IMGSZ) {
      const float* prow = imgb + grow * IMGSZ;
      for (int cb = seg; cb < NCB2; cb += 4) {
        const int cbase = col_a0 + 4 * cb;
        if (cbase >= cend) break;
        float sj[4];
        if (cbase >= 0 && cbase <= IMGSZ - 4) {
          const float4 a  = *reinterpret_cast<const float4*>(prow + cbase);
          const float4 b4 = *reinterpret_cast<const float4*>(prow + IMG2 + cbase);
          const float4 c4 = *reinterpret_cast<const float4*>(prow + 2 * IMG2 + cbase);
          sj[0] = a.x + b4.x + c4.x;
          sj[1] = a.y + b4.y + c4.y;
          sj[2] = a.z + b4.z + c4.z;
          sj[3] = a.w + b4.w + c4.w;
        } else {
          #pragma unroll
          for (int j = 0; j < 4; ++j) {
            const int cc = cbase + j;
            const int ccl = cc < 0 ? 0 : (cc > IMGSZ - 1 ? IMGSZ - 1 : cc);
            const float s = prow[ccl] + prow[IMG2 + ccl] + prow[2 * IMG2 + ccl];
            sj[j] = ((unsigned)cc < (unsigned)IMGSZ) ? s : 0.f;
          }
        }
        float vv[16];
        {
          const float4* vt4 = reinterpret_cast<const float4*>(vt);
          const float4 v0 = vt4[cb + 0];
          const float4 v1 = vt4[cb + 1];
          const float4 v2 = vt4[cb + 2];
          const float4 v3 = vt4[cb + 3];
          vv[0]=v0.x; vv[1]=v0.y; vv[2]=v0.z; vv[3]=v0.w;
          vv[4]=v1.x; vv[5]=v1.y; vv[6]=v1.z; vv[7]=v1.w;
          vv[8]=v2.x; vv[9]=v2.y; vv[10]=v2.z; vv[11]=v2.w;
          vv[12]=v3.x; vv[13]=v3.y; vv[14]=v3.z; vv[15]=v3.w;
        }
        #pragma unroll
        for (int j = 0; j < 4; ++j) {
          #pragma unroll
          for (int ox = 0; ox < 12; ++ox) {
            acc[ox] += sj[j] * vv[11 + j - ox];   // = v[c_rel - ox]
          }
        }
      }
    }

    // reduce 4 segs within the wave (segs sit at lane strides of 16)
    #pragma unroll
    for (int ox = 0; ox < 12; ++ox) {
      acc[ox] += __shfl_down(acc[ox], 32, 64);
      acc[ox] += __shfl_down(acc[ox], 16, 64);
    }
    if (lane < 16) {
      float4* dst = reinterpret_cast<float4*>(&h_lds[w][lane][0]);
      dst[0] = make_float4(acc[0], acc[1], acc[2], acc[3]);
      dst[1] = make_float4(acc[4], acc[5], acc[6], acc[7]);
      dst[2] = make_float4(acc[8], acc[9], acc[10], acc[11]);
    }
    // same-wave LDS write->read: hardware lgkmcnt ordering, no barrier
    const float* ub = ut + 16 + r0;
    #pragma unroll
    for (int r = 0; r < 16; ++r) {
      accA += ub[r - oyA] * h_lds[w][r][oxA];
      accB += ub[r - oyB] * h_lds[w][r][oxB];
      accC += ub[r - oyC] * h_lds[w][r][oxC];
    }
  }

  // combine wave partials
  osum[w][e0] = accA;
  osum[w][e1] = accB;
  if (lane < 16) osum[w][e2] = accC;
  __syncthreads();
  if (tid < 144) {
    out[((size_t)b * 4 + gi) * 144 + tid] =
        osum[0][tid] + osum[1][tid] + osum[2][tid] + osum[3][tid];
  }
}

__global__ __launch_bounds__(256, 4) void glimpse_kernel(
    const float* __restrict__ img, const int* __restrict__ locs,
    const float* __restrict__ k0, const float* __restrict__ k1,
    const float* __restrict__ k2, const float* __restrict__ k3,
    float* __restrict__ out) {
  __shared__ __align__(16) float vt[176];
  __shared__ __align__(16) float ut[160];
  __shared__ __align__(16) float h_lds[4][16][12];
  __shared__ __align__(16) float osum[4][144];
  const int bid = blockIdx.x;
  const int gi = bid & 3;            // interleave glimpse kinds across XCDs
  const int b = bid >> 2;
  switch (gi) {
    case 0:  glimpse_bg<12 >(b, 0, img, locs, k0, out, vt, ut, h_lds, osum); break;
    case 1:  glimpse_bg<23 >(b, 1, img, locs, k1, out, vt, ut, h_lds, osum); break;
    case 2:  glimpse_bg<68 >(b, 2, img, locs, k2, out, vt, ut, h_lds, osum); break;
    default: glimpse_bg<135>(b, 3, img, locs, k3, out, vt, ut, h_lds, osum); break;
  }
}

}  // namespace

extern "C" void kernel_launch(void* const* d_in, const int* in_sizes, int n_in,
                              void* d_out, int out_size, void* d_ws, size_t ws_size,
                              hipStream_t stream) {
  const float* img  = (const float*)d_in[0];
  const int*   locs = (const int*)d_in[1];
  const float* k0   = (const float*)d_in[2];
  const float* k1   = (const float*)d_in[3];
  const float* k2   = (const float*)d_in[4];
  const float* k3   = (const float*)d_in[5];
  float* out = (float*)d_out;

  glimpse_kernel<<<1024, 256, 0, stream>>>(img, locs, k0, k1, k2, k3, out);
}

// Round 9
// 34.494 us; speedup vs baseline: 1.7035x; 1.7035x over previous
//
#include <hip/hip_runtime.h>

namespace {

constexpr int IMGSZ = 224;
constexpr int IMG2  = IMGSZ * IMGSZ;   // 50176

// One block = (b, 32-row chunk of one glimpse). 128 threads = 2 waves, fully
// per-wave (no __syncthreads anywhere): each wave fills its OWN LDS tables
//   vpad2[i] = v[i-11-sh] (176, zero-padded), upad[16+j] = u[j] (160, 0-pad)
// then processes the chunk's two 16-row halves serially (tables reused):
// lanes = (row 0..15) x (seg4 0..3), global seg = wv*4+seg4; runtime column
// loop over image-aligned 4-col blocks with per-iteration interior check
// (round-4 champion structure, NO template split). H[row][ox] =
// sum_c S[row][c]*v[c-ox] via compile-time register window vs the LDS
// v-table. Shfl-reduce 4 segs -> per-wave h_lds[16][12]; same-wave read-back
// accumulates the vertical partial into 3 per-lane registers across both
// halves; one atomicAdd pass per wave at the end.
// k = u v^T (rank-1 bicubic): u[r] = k[r][c0], v[c] = k[c0][c] / k[c0][c0].
// Out-of-crop columns contribute 0 via the zero-padded v-table; out-of-range
// vertical taps contribute 0 via the zero-padded u-table, so padded trailing
// col-blocks / rows need only memory-safe (not exact) loads.
template <int G>
__device__ void chunk_glimpse(
    int b, int gi, int ch,
    const float* __restrict__ img, const int* __restrict__ locs,
    const float* __restrict__ kptr, float* __restrict__ out,
    float* __restrict__ vpad2, float* __restrict__ upad,
    float (*__restrict__ h_lds)[12]) {
  constexpr int KSZ  = G - 11;
  constexpr int C0   = KSZ / 2;
  constexpr int NCB2 = (G + 2) / 4 + 1;    // aligned 4-col blocks (covers sh<=3)
  const int lane = threadIdx.x & 63;

  const int x = locs[2 * b];
  const int y = locs[2 * b + 1];
  const int col0 = y - G / 2;
  const int sh = col0 & 3;                 // floor-mod 4 (works for negative)
  const int col_a0 = col0 - sh;            // image-aligned start
  const int cend = col0 + G;
  const float* imgb = img + (size_t)b * (3 * IMG2);

  // per-wave v table (champion verbatim)
  {
    const float rpiv = 1.0f / kptr[C0 * KSZ + C0];
    for (int i = lane; i < 176; i += 64) {
      const int k = i - 11 - sh;
      vpad2[i] = (k >= 0 && k < KSZ) ? kptr[C0 * KSZ + k] * rpiv : 0.f;
    }
  }
  // per-wave u table
  for (int i = lane; i < 160; i += 64) {
    const int j = i - 16;
    upad[i] = (j >= 0 && j < KSZ) ? kptr[j * KSZ + C0] : 0.f;
  }

  const int row = lane & 15;
  const int seg = (threadIdx.x >> 6) * 4 + (lane >> 4);   // 0..7

  // owned output elements: e0 (all lanes), e1 (all lanes), e2 (lanes<16)
  const int e0 = lane;       const int oyA = e0 / 12, oxA = e0 - oyA * 12;
  const int e1 = lane + 64;  const int oyB = e1 / 12, oxB = e1 - oyB * 12;
  const int e2 = lane + 128; const int oyC = e2 / 12, oxC = e2 - oyC * 12;
  float accA = 0.f, accB = 0.f, accC = 0.f;

  #pragma unroll 1
  for (int half = 0; half < 2; ++half) {
    const int r0 = ch * 32 + half * 16;
    if (r0 >= G) break;                    // wave-uniform
    const int row0 = x - G / 2 + r0;
    const int R = (G - r0) < 16 ? (G - r0) : 16;

    float acc[12];
    #pragma unroll
    for (int i = 0; i < 12; ++i) acc[i] = 0.f;

    const int grow = row0 + row;
    if (row < R && (unsigned)grow < (unsigned)IMGSZ) {
      const float* prow = imgb + grow * IMGSZ;
      for (int cb = seg; cb < NCB2; cb += 8) {
        const int cbase = col_a0 + 4 * cb;
        if (cbase >= cend) break;
        float sj[4];
        if (cbase >= 0 && cbase <= IMGSZ - 4) {
          const float4 a  = *reinterpret_cast<const float4*>(prow + cbase);
          const float4 b4 = *reinterpret_cast<const float4*>(prow + IMG2 + cbase);
          const float4 c4 = *reinterpret_cast<const float4*>(prow + 2 * IMG2 + cbase);
          sj[0] = a.x + b4.x + c4.x;
          sj[1] = a.y + b4.y + c4.y;
          sj[2] = a.z + b4.z + c4.z;
          sj[3] = a.w + b4.w + c4.w;
        } else {
          #pragma unroll
          for (int j = 0; j < 4; ++j) {
            const int cc = cbase + j;
            const int ccl = cc < 0 ? 0 : (cc > IMGSZ - 1 ? IMGSZ - 1 : cc);
            const float s = prow[ccl] + prow[IMG2 + ccl] + prow[2 * IMG2 + ccl];
            sj[j] = ((unsigned)cc < (unsigned)IMGSZ) ? s : 0.f;
          }
        }
        float vv[16];
        {
          const float4* vt4 = reinterpret_cast<const float4*>(vpad2);
          const float4 v0 = vt4[cb + 0];
          const float4 v1 = vt4[cb + 1];
          const float4 v2 = vt4[cb + 2];
          const float4 v3 = vt4[cb + 3];
          vv[0]=v0.x; vv[1]=v0.y; vv[2]=v0.z; vv[3]=v0.w;
          vv[4]=v1.x; vv[5]=v1.y; vv[6]=v1.z; vv[7]=v1.w;
          vv[8]=v2.x; vv[9]=v2.y; vv[10]=v2.z; vv[11]=v2.w;
          vv[12]=v3.x; vv[13]=v3.y; vv[14]=v3.z; vv[15]=v3.w;
        }
        #pragma unroll
        for (int j = 0; j < 4; ++j) {
          #pragma unroll
          for (int ox = 0; ox < 12; ++ox) {
            acc[ox] += sj[j] * vv[11 + j - ox];   // = v[c_rel - ox]
          }
        }
      }
    }

    // reduce 4 segs within the wave (segs sit at lane strides of 16)
    #pragma unroll
    for (int ox = 0; ox < 12; ++ox) {
      acc[ox] += __shfl_down(acc[ox], 32, 64);
      acc[ox] += __shfl_down(acc[ox], 16, 64);
    }
    if (lane < 16) {
      float4* dst = reinterpret_cast<float4*>(&h_lds[lane][0]);
      dst[0] = make_float4(acc[0], acc[1], acc[2], acc[3]);
      dst[1] = make_float4(acc[4], acc[5], acc[6], acc[7]);
      dst[2] = make_float4(acc[8], acc[9], acc[10], acc[11]);
    }
    // same-wave LDS write->read: hardware lgkmcnt ordering, no barrier needed
    const float* ub = upad + 16 + r0;
    #pragma unroll
    for (int r = 0; r < 16; ++r) {
      accA += ub[r - oyA] * h_lds[r][oxA];
      accB += ub[r - oyB] * h_lds[r][oxB];
      accC += ub[r - oyC] * h_lds[r][oxC];
    }
  }

  // per-wave atomic scatter (once per block, both halves accumulated)
  float* outp = out + ((size_t)b * 4 + gi) * 144;
  atomicAdd(&outp[e0], accA);
  atomicAdd(&outp[e1], accB);              // e1 <= 127 < 144 always
  if (lane < 16) atomicAdd(&outp[e2], accC);
}

__global__ __launch_bounds__(128, 6) void glimpse_kernel(
    const float* __restrict__ img, const int* __restrict__ locs,
    const float* __restrict__ k0, const float* __restrict__ k1,
    const float* __restrict__ k2, const float* __restrict__ k3,
    float* __restrict__ out) {
  __shared__ __align__(16) float vpad2[2][176];
  __shared__ __align__(16) float upad[2][160];
  __shared__ __align__(16) float h_lds[2][16][12];
  const int bid = blockIdx.x;
  const int b = bid & 255;
  const int t = bid >> 8;            // 0..9 ; same-b chunks share an XCD
  const int wv = threadIdx.x >> 6;
  if (t == 0) {
    chunk_glimpse<12 >(b, 0, 0,     img, locs, k0, out, vpad2[wv], upad[wv], h_lds[wv]);
  } else if (t == 1) {
    chunk_glimpse<23 >(b, 1, 0,     img, locs, k1, out, vpad2[wv], upad[wv], h_lds[wv]);
  } else if (t < 5) {
    chunk_glimpse<68 >(b, 2, t - 2, img, locs, k2, out, vpad2[wv], upad[wv], h_lds[wv]);
  } else {
    chunk_glimpse<135>(b, 3, t - 5, img, locs, k3, out, vpad2[wv], upad[wv], h_lds[wv]);
  }
}

}  // namespace

extern "C" void kernel_launch(void* const* d_in, const int* in_sizes, int n_in,
                              void* d_out, int out_size, void* d_ws, size_t ws_size,
                              hipStream_t stream) {
  const float* img  = (const float*)d_in[0];
  const int*   locs = (const int*)d_in[1];
  const float* k0   = (const float*)d_in[2];
  const float* k1   = (const float*)d_in[3];
  const float* k2   = (const float*)d_in[4];
  const float* k3   = (const float*)d_in[5];
  float* out = (float*)d_out;

  hipMemsetAsync(out, 0, (size_t)out_size * sizeof(float), stream);
  glimpse_kernel<<<256 * 10, 128, 0, stream>>>(img, locs, k0, k1, k2, k3, out);
}